// Round 3
// baseline (560.249 us; speedup 1.0000x reference)
//
#include <hip/hip_runtime.h>
#include <hip/hip_bf16.h>
#include <stdint.h>
#include <stddef.h>

#define IN_F   4096
#define OUT_F  4096
#define RANK   16
#define GROUP  128
#define M_TOT  8192   // 8 * 1024

// ---- GEMM geometry: 256x256 tile, BK=32, 8 waves, 3-deep counted-vmcnt pipe
#define BM     256
#define BN     256
#define BK     32
#define NIT    (IN_F / BK)        // 128 K-tiles
#define HALF_B 16384              // one A- or B-tile: 256*32*2B
#define TILE_B 32768              // A+B per K-tile
#define LDS_B  (3 * TILE_B)       // 96 KiB dynamic LDS

typedef __bf16 bf16_t;
typedef __bf16 bf16x4 __attribute__((ext_vector_type(4)));
typedef __bf16 bf16x8 __attribute__((ext_vector_type(8)));
typedef float  f32x4  __attribute__((ext_vector_type(4)));

// ---------------------------------------------------------------------------
// async global -> LDS, 16B per lane. LDS dest is wave-uniform base + lane*16.
// ---------------------------------------------------------------------------
__device__ static inline void load_lds16(const void* g, void* l) {
  __builtin_amdgcn_global_load_lds(
      (const __attribute__((address_space(1))) unsigned int*)g,
      (__attribute__((address_space(3))) unsigned int*)l,
      16, 0, 0);
}

// ---------------------------------------------------------------------------
// Kernel 1: w_q = fake-quant(w0 + lora_b @ lora_a)  (unchanged, BW-bound)
// ---------------------------------------------------------------------------
__global__ void __launch_bounds__(256)
quant_kernel(const float* __restrict__ w0, const float* __restrict__ la,
             const float* __restrict__ lb, const float* __restrict__ qs,
             bf16_t* __restrict__ wq)
{
  const int o = blockIdx.y;                            // output row
  const int i = blockIdx.x * 1024 + threadIdx.x * 4;   // column (x4)

  __shared__ float lbr[RANK];
  if (threadIdx.x < RANK) lbr[threadIdx.x] = lb[o * RANK + threadIdx.x];
  __syncthreads();

  const size_t off = (size_t)o * IN_F + i;
  const float4 w = *(const float4*)(w0 + off);
  float a0 = w.x, a1 = w.y, a2 = w.z, a3 = w.w;
  #pragma unroll
  for (int r = 0; r < RANK; ++r) {
    const float4 av = *(const float4*)(la + (size_t)r * IN_F + i);
    const float bv = lbr[r];
    a0 = fmaf(bv, av.x, a0);
    a1 = fmaf(bv, av.y, a1);
    a2 = fmaf(bv, av.z, a2);
    a3 = fmaf(bv, av.w, a3);
  }
  const float s   = qs[o * (IN_F / GROUP) + (i >> 7)];
  const float inv = 1.0f / (s + 1e-9f);
  const float q0 = rintf(fminf(fmaxf(a0 * inv, -8.0f), 7.0f)) * s;
  const float q1 = rintf(fminf(fmaxf(a1 * inv, -8.0f), 7.0f)) * s;
  const float q2 = rintf(fminf(fmaxf(a2 * inv, -8.0f), 7.0f)) * s;
  const float q3 = rintf(fminf(fmaxf(a3 * inv, -8.0f), 7.0f)) * s;
  bf16x4 v;
  v[0] = (bf16_t)q0; v[1] = (bf16_t)q1; v[2] = (bf16_t)q2; v[3] = (bf16_t)q3;
  *(bf16x4*)(wq + off) = v;
}

// ---------------------------------------------------------------------------
// Kernel 2: x fp32 -> bf16 (RNE)  (unchanged, at BW floor)
// ---------------------------------------------------------------------------
__global__ void __launch_bounds__(256)
castx_kernel(const float* __restrict__ x, bf16_t* __restrict__ xb)
{
  const size_t i = ((size_t)blockIdx.x * 256 + threadIdx.x) * 8;
  const float4 a = *(const float4*)(x + i);
  const float4 b = *(const float4*)(x + i + 4);
  bf16x8 v;
  v[0] = (bf16_t)a.x; v[1] = (bf16_t)a.y; v[2] = (bf16_t)a.z; v[3] = (bf16_t)a.w;
  v[4] = (bf16_t)b.x; v[5] = (bf16_t)b.y; v[6] = (bf16_t)b.z; v[7] = (bf16_t)b.w;
  *(bf16x8*)(xb + i) = v;
}

// ---------------------------------------------------------------------------
// Kernel 3: GEMM  C[m][n] = sum_k A[m][k] * Bw[n][k] + bias[n]
//
// v6: attack LDS<->MFMA serialization (R2 showed dur = LDS_cyc + MFMA_cyc,
// i.e. zero overlap; cause hypothesized: in-order issue + saturated LDS queue
// stalling read-issue ahead of the MFMA cluster).
//  (1) ONE barrier per K-tile (odd-phase top). Both gload stages moved to the
//      odd region. WAR proof: a wave passing odd(T) barrier has passed its
//      even(T) lgkm-wait; lgkm FIFO => ALL its reads of buf((T-1)%3) are
//      complete => stage(T+2) into that buffer is safe.
//  (2) sched_group_barrier interleave per phase: MFMAs lead and read/gload
//      issues are slotted between them, so a read-issue stall never starves
//      the matrix pipe.
// vmcnt(0) publish at odd top waits only 4 gloads issued one full K-tile
// (~2000+ cyc) earlier -- drained in time, not a hot drain.
// ---------------------------------------------------------------------------
__global__ void __launch_bounds__(512, 2)
gemm_kernel(const bf16_t* __restrict__ A, const bf16_t* __restrict__ Bw,
            const float* __restrict__ bias, float* __restrict__ C)
{
  extern __shared__ __align__(16) char smem[];   // 3 * 32 KiB

  const int tid  = threadIdx.x;
  const int lane = tid & 63;
  const int lr   = lane & 15;    // frag row / C col
  const int quad = lane >> 4;    // 0..3
  const int wid  = tid >> 6;     // 0..7
  const int wm   = wid >> 2;     // 0..1  -> rows [wm*128, wm*128+128)
  const int wn   = wid & 3;      // 0..3  -> cols [wn*64,  wn*64+64)

  // XCD-aware bijective swizzle: 512 blocks, 8 XCDs, 64 blocks/XCD chunk.
  const int bid = blockIdx.x;
  const int swz = (bid & 7) * 64 + (bid >> 3);
  const int m0  = (swz >> 4) * BM;   // 32 m-blocks
  const int n0  = (swz & 15) * BN;   // 16 n-blocks

  // staging: thread covers LDS bytes [tid*16, tid*16+16) of a [128][32] half
  // (+8192 for rows 128..255). SOURCE column pre-swizzled so linear LDS dest
  // + swizzled ds_read round-trip (global_load_lds writes linearly).
  const int srow = tid >> 2;                              // 0..127
  const int scol = ((tid & 3) ^ ((tid >> 3) & 3)) * 8;    // bf16 offset
  const bf16_t* gA0 = A  + (size_t)(m0 + srow) * IN_F + scol;
  const bf16_t* gA1 = gA0 + (size_t)128 * IN_F;
  const bf16_t* gB0 = Bw + (size_t)(n0 + srow) * IN_F + scol;
  const bf16_t* gB1 = gB0 + (size_t)128 * IN_F;

  // per-thread LDS read offsets (bytes) inside a 16 KiB half
  const int rswz = (quad ^ ((lr >> 1) & 3)) * 16;   // swizzled 16B slot
  const int aOff = (wm * 128 + lr) * 64 + rswz;
  const int bOff = (wn * 64  + lr) * 64 + rswz;

  f32x4 acc[8][4];
  #pragma unroll
  for (int i = 0; i < 8; ++i)
    #pragma unroll
    for (int j = 0; j < 4; ++j)
      acc[i][j] = (f32x4){0.f, 0.f, 0.f, 0.f};

  bf16x8 bfr0[4], bfr1[4], afA[4], afB[4];

  auto stageA = [&](int T, char* buf) {
    const size_t ko = (size_t)T * BK;
    load_lds16(gA0 + ko, buf + tid * 16);
    load_lds16(gA1 + ko, buf + tid * 16 + 8192);
  };
  auto stageB = [&](int T, char* buf) {
    const size_t ko = (size_t)T * BK;
    load_lds16(gB0 + ko, buf + HALF_B + tid * 16);
    load_lds16(gB1 + ko, buf + HALF_B + tid * 16 + 8192);
  };

  // even phase of K-tile T: no barrier. Read afB(T); MFMA fm0-3 on
  // {afA(T), bcur}. SGB: 2 MFMA lead each DS_READ issue.
  auto ph_even = [&](int T, const char* rbuf, bf16x8 (&bcur)[4]) {
    __builtin_amdgcn_s_setprio(1);
    #pragma unroll
    for (int f = 0; f < 4; ++f)
      afB[f] = *(const bf16x8*)(rbuf + aOff + 4096 + f * 1024);
    #pragma unroll
    for (int fm = 0; fm < 4; ++fm)
      #pragma unroll
      for (int fn = 0; fn < 4; ++fn)
        acc[fm][fn] = __builtin_amdgcn_mfma_f32_16x16x32_bf16(
            afA[fm], bcur[fn], acc[fm][fn], 0, 0, 0);
    #pragma unroll
    for (int g = 0; g < 4; ++g) {
      __builtin_amdgcn_sched_group_barrier(0x008, 2, 0);  // 2 MFMA
      __builtin_amdgcn_sched_group_barrier(0x100, 1, 0);  // 1 DS read
    }
    __builtin_amdgcn_sched_group_barrier(0x008, 8, 0);    // tail MFMAs
    __builtin_amdgcn_s_setprio(0);
    __builtin_amdgcn_sched_barrier(0);
  };

  // odd phase of K-tile T: publish T+1 (vmcnt(0) of loads issued one K-tile
  // ago + barrier); stage T+2; prefetch bnxt+afA(T+1); MFMA fm4-7 on
  // {afB(T), bcur}. SGB: MFMAs lead, gloads + reads slotted between.
  auto ph_odd = [&](int T, const char* rnext, char* wbuf,
                    bf16x8 (&bcur)[4], bf16x8 (&bnxt)[4]) {
    asm volatile("s_waitcnt vmcnt(0)" ::: "memory");
    __builtin_amdgcn_s_barrier();
    __builtin_amdgcn_sched_barrier(0);
    __builtin_amdgcn_s_setprio(1);
    if (T + 2 < NIT) { stageA(T + 2, wbuf); stageB(T + 2, wbuf); }
    if (T + 1 < NIT) {
      #pragma unroll
      for (int f = 0; f < 4; ++f)
        bnxt[f] = *(const bf16x8*)(rnext + HALF_B + bOff + f * 1024);
      #pragma unroll
      for (int f = 0; f < 4; ++f)
        afA[f] = *(const bf16x8*)(rnext + aOff + f * 1024);
    }
    #pragma unroll
    for (int fm = 0; fm < 4; ++fm)
      #pragma unroll
      for (int fn = 0; fn < 4; ++fn)
        acc[4 + fm][fn] = __builtin_amdgcn_mfma_f32_16x16x32_bf16(
            afB[fm], bcur[fn], acc[4 + fm][fn], 0, 0, 0);
    #pragma unroll
    for (int g = 0; g < 4; ++g) {
      __builtin_amdgcn_sched_group_barrier(0x008, 1, 0);  // 1 MFMA
      __builtin_amdgcn_sched_group_barrier(0x010, 1, 0);  // 1 gload(VMEM)
    }
    #pragma unroll
    for (int g = 0; g < 8; ++g) {
      __builtin_amdgcn_sched_group_barrier(0x008, 1, 0);  // 1 MFMA
      __builtin_amdgcn_sched_group_barrier(0x100, 1, 0);  // 1 DS read
    }
    __builtin_amdgcn_sched_group_barrier(0x008, 4, 0);    // tail MFMAs
    __builtin_amdgcn_s_setprio(0);
    __builtin_amdgcn_sched_barrier(0);
  };

  // ---- prologue: stage tiles 0,1; publish tile 0; prefetch bfr0+afA(tile 0)
  {
    stageA(0, smem);          stageB(0, smem);
    stageA(1, smem + TILE_B); stageB(1, smem + TILE_B);
    asm volatile("s_waitcnt vmcnt(4)" ::: "memory");
    __builtin_amdgcn_s_barrier();
    __builtin_amdgcn_sched_barrier(0);
    #pragma unroll
    for (int f = 0; f < 4; ++f)
      bfr0[f] = *(const bf16x8*)(smem + HALF_B + bOff + f * 1024);
    #pragma unroll
    for (int f = 0; f < 4; ++f)
      afA[f] = *(const bf16x8*)(smem + aOff + f * 1024);
  }

  int rb = 0;
  for (int tt = 0; tt < NIT; tt += 2) {
    const int rb1 = (rb + 1 == 3) ? 0 : rb + 1;
    const int rb2 = (rb1 + 1 == 3) ? 0 : rb1 + 1;
    char* b_rb  = smem + rb  * TILE_B;
    char* b_rb1 = smem + rb1 * TILE_B;
    char* b_rb2 = smem + rb2 * TILE_B;

    // K-tile tt   : read b_rb,  stage tile tt+2 -> b_rb2, bfr parity 0
    ph_even(tt,     b_rb,  bfr0);
    ph_odd (tt,     b_rb1, b_rb2, bfr0, bfr1);
    // K-tile tt+1 : read b_rb1, stage tile tt+3 -> b_rb,  bfr parity 1
    ph_even(tt + 1, b_rb1, bfr1);
    ph_odd (tt + 1, b_rb2, b_rb,  bfr1, bfr0);

    rb = rb2;
  }

  // Epilogue: C/D layout col = lane&15, row = quad*4 + reg (m89-verified)
  #pragma unroll
  for (int fn = 0; fn < 4; ++fn) {
    const int gn = n0 + wn * 64 + fn * 16 + lr;
    const float bv = bias[gn];
    #pragma unroll
    for (int fm = 0; fm < 8; ++fm) {
      const int gm = m0 + wm * 128 + fm * 16 + quad * 4;
      #pragma unroll
      for (int r = 0; r < 4; ++r)
        C[(size_t)(gm + r) * OUT_F + gn] = acc[fm][fn][r] + bv;
    }
  }
}

// ---------------------------------------------------------------------------
extern "C" void kernel_launch(void* const* d_in, const int* in_sizes, int n_in,
                              void* d_out, int out_size, void* d_ws, size_t ws_size,
                              hipStream_t stream) {
  const float* x    = (const float*)d_in[0];  // [8,1024,4096]
  const float* w0   = (const float*)d_in[1];  // [4096,4096]
  const float* la   = (const float*)d_in[2];  // [16,4096]
  const float* lb   = (const float*)d_in[3];  // [4096,16]
  const float* qs   = (const float*)d_in[4];  // [131072]
  const float* bias = (const float*)d_in[5];  // [4096]
  float* out = (float*)d_out;                 // [8,1024,4096] fp32

  bf16_t* wq = (bf16_t*)d_ws;                                         // 32 MiB
  bf16_t* xb = (bf16_t*)((char*)d_ws + (size_t)OUT_F * IN_F * 2);     // 64 MiB

  static bool attr_done = false;
  if (!attr_done) {
    (void)hipFuncSetAttribute((const void*)gemm_kernel,
                              hipFuncAttributeMaxDynamicSharedMemorySize,
                              LDS_B);
    attr_done = true;
  }

  quant_kernel<<<dim3(IN_F / 1024, OUT_F), 256, 0, stream>>>(w0, la, lb, qs, wq);
  castx_kernel<<<(M_TOT * IN_F) / (256 * 8), 256, 0, stream>>>(x, xb);
  gemm_kernel<<<dim3((M_TOT / BM) * (OUT_F / BN)), 512, LDS_B, stream>>>(
      xb, wq, bias, out);
}

// Round 4
// 529.885 us; speedup vs baseline: 1.0573x; 1.0573x over previous
//
#include <hip/hip_runtime.h>
#include <hip/hip_bf16.h>
#include <stdint.h>
#include <stddef.h>

#define IN_F   4096
#define OUT_F  4096
#define RANK   16
#define GROUP  128
#define M_TOT  8192   // 8 * 1024

// ---- GEMM geometry: 256x256 tile, K-step 64, 8 waves, m201 8-phase schedule
#define BM     256
#define BN     256
#define BK     64
#define NKS    (IN_F / BK)        // 64 K-steps
#define BUF_B  65536              // one K-step buffer: A 32K + B 32K
#define LDS_B  (2 * BUF_B)        // 128 KiB dynamic LDS

typedef __bf16 bf16_t;
typedef __bf16 bf16x4 __attribute__((ext_vector_type(4)));
typedef __bf16 bf16x8 __attribute__((ext_vector_type(8)));
typedef float  f32x4  __attribute__((ext_vector_type(4)));

// ---------------------------------------------------------------------------
// async global -> LDS, 16B per lane. LDS dest is wave-uniform base + lane*16.
// ---------------------------------------------------------------------------
__device__ static inline void load_lds16(const void* g, void* l) {
  __builtin_amdgcn_global_load_lds(
      (const __attribute__((address_space(1))) unsigned int*)g,
      (__attribute__((address_space(3))) unsigned int*)l,
      16, 0, 0);
}

// ---------------------------------------------------------------------------
// Kernel 1: w_q = fake-quant(w0 + lora_b @ lora_a)  (unchanged, BW-bound)
// ---------------------------------------------------------------------------
__global__ void __launch_bounds__(256)
quant_kernel(const float* __restrict__ w0, const float* __restrict__ la,
             const float* __restrict__ lb, const float* __restrict__ qs,
             bf16_t* __restrict__ wq)
{
  const int o = blockIdx.y;                            // output row
  const int i = blockIdx.x * 1024 + threadIdx.x * 4;   // column (x4)

  __shared__ float lbr[RANK];
  if (threadIdx.x < RANK) lbr[threadIdx.x] = lb[o * RANK + threadIdx.x];
  __syncthreads();

  const size_t off = (size_t)o * IN_F + i;
  const float4 w = *(const float4*)(w0 + off);
  float a0 = w.x, a1 = w.y, a2 = w.z, a3 = w.w;
  #pragma unroll
  for (int r = 0; r < RANK; ++r) {
    const float4 av = *(const float4*)(la + (size_t)r * IN_F + i);
    const float bv = lbr[r];
    a0 = fmaf(bv, av.x, a0);
    a1 = fmaf(bv, av.y, a1);
    a2 = fmaf(bv, av.z, a2);
    a3 = fmaf(bv, av.w, a3);
  }
  const float s   = qs[o * (IN_F / GROUP) + (i >> 7)];
  const float inv = 1.0f / (s + 1e-9f);
  const float q0 = rintf(fminf(fmaxf(a0 * inv, -8.0f), 7.0f)) * s;
  const float q1 = rintf(fminf(fmaxf(a1 * inv, -8.0f), 7.0f)) * s;
  const float q2 = rintf(fminf(fmaxf(a2 * inv, -8.0f), 7.0f)) * s;
  const float q3 = rintf(fminf(fmaxf(a3 * inv, -8.0f), 7.0f)) * s;
  bf16x4 v;
  v[0] = (bf16_t)q0; v[1] = (bf16_t)q1; v[2] = (bf16_t)q2; v[3] = (bf16_t)q3;
  *(bf16x4*)(wq + off) = v;
}

// ---------------------------------------------------------------------------
// Kernel 2: x fp32 -> bf16 (RNE)  (unchanged, at BW floor)
// ---------------------------------------------------------------------------
__global__ void __launch_bounds__(256)
castx_kernel(const float* __restrict__ x, bf16_t* __restrict__ xb)
{
  const size_t i = ((size_t)blockIdx.x * 256 + threadIdx.x) * 8;
  const float4 a = *(const float4*)(x + i);
  const float4 b = *(const float4*)(x + i + 4);
  bf16x8 v;
  v[0] = (bf16_t)a.x; v[1] = (bf16_t)a.y; v[2] = (bf16_t)a.z; v[3] = (bf16_t)a.w;
  v[4] = (bf16_t)b.x; v[5] = (bf16_t)b.y; v[6] = (bf16_t)b.z; v[7] = (bf16_t)b.w;
  *(bf16x8*)(xb + i) = v;
}

// ---------------------------------------------------------------------------
// Kernel 3: GEMM  C[m][n] = sum_k A[m][k] * Bw[n][k] + bias[n]
//
// v7: faithful port of the verified 256^2 8-phase schedule (m201). BK=64,
// 8 waves (2M x 4N, 128x64/wave), 4 phases per K-step, 2 x 64KB LDS buffers.
// Phase p: {ds_reads for THIS phase | stage half-tile} -> barrier ->
// lgkmcnt(0)+sched_barrier(0) -> setprio(1) -> 16 MFMA -> setprio(0) ->
// barrier. Counted vmcnt(4) ONCE per K-step (ph3); never a hot drain.
//
// B frags (8 x b128) hoisted to regs at ph0, reused ph1-3 -> B LDS slots of
// the CURRENT buffer are dead after ph0 (every wave's lgkmcnt(0) precedes its
// MFMA precedes ph0-end barrier) -> stage B(ks+2) into them at ph1/ph2.
// A(ks+1) stages into the OTHER buffer at ph0/ph1 (its last reads completed
// before the previous K-step's final barrier). All stage targets are
// barrier-separated from their last readers: race-free by construction.
//
// vmcnt(4) at ph3 leaves exactly B(ks+2)'s 4 loads in flight; vmem FIFO =>
// A(ks+1) and B(ks+1) (older) have landed. ks==NKS-2: vmcnt(0) drains A.
//
// Swizzle (128B rows, 8 slots): phys_slot = chunk ^ (row&7). Per 8-lane
// service group all 8 slots distinct -> conflict-free ds_read_b128. Staging
// source pre-swizzled with the same involution (both-sides rule).
// ---------------------------------------------------------------------------
__global__ void __launch_bounds__(512, 2)
gemm_kernel(const bf16_t* __restrict__ A, const bf16_t* __restrict__ Bw,
            const float* __restrict__ bias, float* __restrict__ C)
{
  extern __shared__ __align__(16) char smem[];   // 2 x 64 KiB

  const int tid  = threadIdx.x;
  const int lane = tid & 63;
  const int lr   = lane & 15;    // frag row / C col
  const int quad = lane >> 4;    // 0..3
  const int wid  = tid >> 6;     // 0..7
  const int wm   = wid >> 2;     // 0..1  -> rows [wm*128, wm*128+128)
  const int wn   = wid & 3;      // 0..3  -> cols [wn*64,  wn*64+64)

  // XCD-aware bijective swizzle: 512 blocks, 8 XCDs, 64 blocks/XCD chunk.
  const int bid = blockIdx.x;
  const int swz = (bid & 7) * 64 + (bid >> 3);
  const int m0  = (swz >> 4) * BM;   // 32 m-blocks
  const int n0  = (swz & 15) * BN;   // 16 n-blocks

  // staging: half-tile = 128 rows x 64 cols bf16 = 16KB = 2 gloads.
  // thread t covers (row = t>>3 [+64 for 2nd gload], phys slot = t&7).
  // source chunk pre-swizzled: c = slot ^ (row&7).
  const int srow = tid >> 3;                              // 0..63
  const int scol = ((tid & 7) ^ (srow & 7)) * 8;          // bf16 offset
  const bf16_t* gA = A  + (size_t)(m0 + srow) * IN_F + scol;
  const bf16_t* gB = Bw + (size_t)(n0 + srow) * IN_F + scol;
  const bf16_t* gA1 = gA + (size_t)128 * IN_F;
  const bf16_t* gB1 = gB + (size_t)128 * IN_F;

  // LDS read bases (byte offsets within a 64KB buffer).
  // buf layout: A0@0, A1@16384, B0@32768, B1@49152 (each 16KB, 128B rows).
  // frag read: row*128 + ((chunk) ^ (row&7))*16, chunk = kk*4+quad.
  const int sslot = (quad ^ (lr & 7)) * 16;     // kk applied as ^ (kk<<6)
  const int aBase = wm * 16384 + lr * 128 + sslot;                 // + p*4096 + i*2048
  const int bBase = 32768 + (wn >> 1) * 16384 + (wn & 1) * 8192
                  + lr * 128 + sslot;                              // + fn*2048

  f32x4 acc[8][4];
  #pragma unroll
  for (int i = 0; i < 8; ++i)
    #pragma unroll
    for (int j = 0; j < 4; ++j)
      acc[i][j] = (f32x4){0.f, 0.f, 0.f, 0.f};

  bf16x8 bfr[4][2];   // B frags, whole K-step (read at ph0)
  bf16x8 af[2][2];    // A frags, per phase

  auto stageHalf = [&](const bf16_t* g0, int ks, char* halfdst) {
    const bf16_t* g = g0 + (size_t)ks * BK;
    load_lds16(g, halfdst + tid * 16);
    load_lds16(g + (size_t)64 * IN_F, halfdst + tid * 16 + 8192);
  };

  // ---- prologue: B(0), A(0), B(1); vmcnt(4) leaves B(1) in flight
  stageHalf(gB,  0, smem + 32768);
  stageHalf(gB1, 0, smem + 49152);
  stageHalf(gA,  0, smem + 0);
  stageHalf(gA1, 0, smem + 16384);
  stageHalf(gB,  1, smem + BUF_B + 32768);
  stageHalf(gB1, 1, smem + BUF_B + 49152);
  asm volatile("s_waitcnt vmcnt(4)" ::: "memory");
  __builtin_amdgcn_s_barrier();

  for (int ks = 0; ks < NKS; ++ks) {
    char* rbuf = smem + (ks & 1) * BUF_B;        // current K-step
    char* obuf = smem + ((ks & 1) ^ 1) * BUF_B;  // other buffer

    #pragma unroll
    for (int p = 0; p < 4; ++p) {
      // ---- ds reads for THIS phase
      if (p == 0) {
        #pragma unroll
        for (int fn = 0; fn < 4; ++fn)
          #pragma unroll
          for (int kk = 0; kk < 2; ++kk)
            bfr[fn][kk] = *(const bf16x8*)(rbuf + ((bBase + fn * 2048) ^ (kk << 6)));
      }
      #pragma unroll
      for (int i = 0; i < 2; ++i)
        #pragma unroll
        for (int kk = 0; kk < 2; ++kk)
          af[i][kk] = *(const bf16x8*)(rbuf + ((aBase + p * 4096 + i * 2048) ^ (kk << 6)));

      // ---- staging cadence (1-2 half-tiles per phase)
      if (p == 0 && ks + 1 < NKS) stageHalf(gA,  ks + 1, obuf + 0);
      if (p == 1) {
        if (ks + 1 < NKS) stageHalf(gA1, ks + 1, obuf + 16384);
        if (ks + 2 < NKS) stageHalf(gB,  ks + 2, rbuf + 32768);  // dead B0 slot
      }
      if (p == 2 && ks + 2 < NKS) stageHalf(gB1, ks + 2, rbuf + 49152);

      __builtin_amdgcn_s_barrier();
      asm volatile("s_waitcnt lgkmcnt(0)" ::: "memory");
      __builtin_amdgcn_sched_barrier(0);
      __builtin_amdgcn_s_setprio(1);
      #pragma unroll
      for (int kk = 0; kk < 2; ++kk)
        #pragma unroll
        for (int i = 0; i < 2; ++i)
          #pragma unroll
          for (int fn = 0; fn < 4; ++fn)
            acc[2 * p + i][fn] = __builtin_amdgcn_mfma_f32_16x16x32_bf16(
                af[i][kk], bfr[fn][kk], acc[2 * p + i][fn], 0, 0, 0);
      __builtin_amdgcn_s_setprio(0);
      if (p == 3) {
        if (ks + 2 < NKS)      asm volatile("s_waitcnt vmcnt(4)" ::: "memory");
        else if (ks + 1 < NKS) asm volatile("s_waitcnt vmcnt(0)" ::: "memory");
      }
      __builtin_amdgcn_s_barrier();
    }
  }

  // Epilogue: C/D layout col = lane&15, row = quad*4 + reg (m89-verified)
  #pragma unroll
  for (int fn = 0; fn < 4; ++fn) {
    const int gn = n0 + wn * 64 + fn * 16 + lr;
    const float bv = bias[gn];
    #pragma unroll
    for (int fm = 0; fm < 8; ++fm) {
      const int gm = m0 + wm * 128 + fm * 16 + quad * 4;
      #pragma unroll
      for (int r = 0; r < 4; ++r)
        C[(size_t)(gm + r) * OUT_F + gn] = acc[fm][fn][r] + bv;
    }
  }
}

// ---------------------------------------------------------------------------
extern "C" void kernel_launch(void* const* d_in, const int* in_sizes, int n_in,
                              void* d_out, int out_size, void* d_ws, size_t ws_size,
                              hipStream_t stream) {
  const float* x    = (const float*)d_in[0];  // [8,1024,4096]
  const float* w0   = (const float*)d_in[1];  // [4096,4096]
  const float* la   = (const float*)d_in[2];  // [16,4096]
  const float* lb   = (const float*)d_in[3];  // [4096,16]
  const float* qs   = (const float*)d_in[4];  // [131072]
  const float* bias = (const float*)d_in[5];  // [4096]
  float* out = (float*)d_out;                 // [8,1024,4096] fp32

  bf16_t* wq = (bf16_t*)d_ws;                                         // 32 MiB
  bf16_t* xb = (bf16_t*)((char*)d_ws + (size_t)OUT_F * IN_F * 2);     // 64 MiB

  static bool attr_done = false;
  if (!attr_done) {
    (void)hipFuncSetAttribute((const void*)gemm_kernel,
                              hipFuncAttributeMaxDynamicSharedMemorySize,
                              LDS_B);
    attr_done = true;
  }

  quant_kernel<<<dim3(IN_F / 1024, OUT_F), 256, 0, stream>>>(w0, la, lb, qs, wq);
  castx_kernel<<<(M_TOT * IN_F) / (256 * 8), 256, 0, stream>>>(x, xb);
  gemm_kernel<<<dim3((M_TOT / BM) * (OUT_F / BN)), 512, LDS_B, stream>>>(
      xb, wq, bias, out);
}